// Round 2
// baseline (2003.160 us; speedup 1.0000x reference)
//
#include <hip/hip_runtime.h>
#include <stdint.h>

// CausalMultiHeadAttention — round 2.
// Inputs/outputs are fp32 in memory (round-1 NaN proved bf16-view is wrong:
// low halves of fp32 words decode as bf16 NaNs). Compute is bf16 MFMA
// (2%-of-max threshold licenses it). Pipeline:
//   1) Q/K/V projections: fp32 in -> bf16 LDS staging -> MFMA -> bf16 ws
//      (head-major; Q pre-scaled by 1/8, exact in bf16)
//   2) causal flash attention, fp32 VALU, one thread per query row (bf16 ws in/out)
//   3) output projection: bf16 O @ fp32 Wo^T -> fp32 d_out
// ws: Q | K | V | O, bf16, 16 MB each = 64 MB.

#define D_MODEL 1024
#define NHEAD   16
#define DK      64
#define BATCH   4
#define SEQ     2048
#define MTOT    (BATCH*SEQ)   // 8192

typedef unsigned short u16;
typedef unsigned int   u32;
typedef __bf16  bf16x8  __attribute__((ext_vector_type(8)));
typedef float   floatx4 __attribute__((ext_vector_type(4)));

__device__ __forceinline__ float bflo(u32 u){
  union { u32 u; float f; } c; c.u = u << 16; return c.f;
}
__device__ __forceinline__ float bfhi(u32 u){
  union { u32 u; float f; } c; c.u = u & 0xffff0000u; return c.f;
}
// round-to-nearest-even f32 -> bf16 (inputs are finite)
__device__ __forceinline__ u16 f2bf(float f){
  union { float f; u32 u; } c; c.f = f;
  u32 x = c.u;
  x += 0x7fffu + ((x >> 16) & 1u);
  return (u16)(x >> 16);
}
// load 8 fp32, round to bf16, pack as uint4 (16 B) for LDS staging
__device__ __forceinline__ uint4 cvt8(const float* __restrict__ p){
  float4 a = *(const float4*)p;
  float4 b = *(const float4*)(p + 4);
  uint4 r;
  r.x = ((u32)f2bf(a.y) << 16) | f2bf(a.x);
  r.y = ((u32)f2bf(a.w) << 16) | f2bf(a.z);
  r.z = ((u32)f2bf(b.y) << 16) | f2bf(b.x);
  r.w = ((u32)f2bf(b.w) << 16) | f2bf(b.z);
  return r;
}

// ---------------------------------------------------------------------------
// GEMM: C[m,n] = sum_k A[m,k] * W[n,k] + bias[n]
// A: MxK, fp32 (AF32=1) or bf16 (AF32=0), row-major. W: NxK fp32 row-major
// (nn.Linear weight = B^T layout) -> both operands read 8 contiguous k per
// lane, matching mfma_16x16x32_bf16 fragments (verified m89/m91/m92 mapping):
//   A frag: m=lane&15, k=(lane>>4)*8+j ; B frag: n=lane&15, k=(lane>>4)*8+j
//   C/D   : n=lane&15, m=(lane>>4)*4+reg
// MODE 0: out fp32 [m*N+n] (final projection -> d_out)
// MODE 1: out bf16 [((b*16+h)*2048+s)*64+d], head-major for attention, *scale
// 64x64 tile, BK=32, 256 threads = 4 waves in 2x2, each wave 32x32 (2x2 MFMA).
// ---------------------------------------------------------------------------
template<int MODE, int AF32>
__global__ __launch_bounds__(256, 4)
void gemm_bt(const void* __restrict__ Av, const float* __restrict__ W,
             const float* __restrict__ bias, void* __restrict__ outv,
             int M, int N, int K, float scale)
{
  // pad 32 -> 40 bf16 (80 B) so frag reads avoid pow-2 bank aliasing
  __shared__ __align__(16) u16 As[64][40];
  __shared__ __align__(16) u16 Bs[64][40];

  const int t    = threadIdx.x;
  const int m0   = blockIdx.y * 64;
  const int n0   = blockIdx.x * 64;
  const int wid  = t >> 6;
  const int lane = t & 63;
  const int wr   = wid >> 1;        // wave row (0..1) -> 32 rows of M
  const int wc   = wid & 1;         // wave col (0..1) -> 32 cols of N
  const int q    = lane >> 4;       // quad 0..3
  const int mr   = lane & 15;

  // staging: each thread covers 8 k-elements (one 16B bf16 chunk) per K-step
  const int srow = t >> 2;
  const int sc   = (t & 3) * 8;
  const float* Af = (const float*)Av;
  const u16*   Ab = (const u16*)Av;
  const size_t aoff = (size_t)(m0 + srow) * K + sc;
  const size_t woff = (size_t)(n0 + srow) * K + sc;

  floatx4 acc[2][2] = {};

  for (int k0 = 0; k0 < K; k0 += 32) {
    __syncthreads();                       // previous iter's frag reads done
    if (AF32) *(uint4*)&As[srow][sc] = cvt8(Af + aoff + k0);
    else      *(uint4*)&As[srow][sc] = *(const uint4*)(Ab + aoff + k0);
    *(uint4*)&Bs[srow][sc] = cvt8(W + woff + k0);
    __syncthreads();

    bf16x8 af0 = *(const bf16x8*)&As[wr*32      + mr][q*8];
    bf16x8 af1 = *(const bf16x8*)&As[wr*32 + 16 + mr][q*8];
    bf16x8 bf0 = *(const bf16x8*)&Bs[wc*32      + mr][q*8];
    bf16x8 bf1 = *(const bf16x8*)&Bs[wc*32 + 16 + mr][q*8];

    acc[0][0] = __builtin_amdgcn_mfma_f32_16x16x32_bf16(af0, bf0, acc[0][0], 0, 0, 0);
    acc[0][1] = __builtin_amdgcn_mfma_f32_16x16x32_bf16(af0, bf1, acc[0][1], 0, 0, 0);
    acc[1][0] = __builtin_amdgcn_mfma_f32_16x16x32_bf16(af1, bf0, acc[1][0], 0, 0, 0);
    acc[1][1] = __builtin_amdgcn_mfma_f32_16x16x32_bf16(af1, bf1, acc[1][1], 0, 0, 0);
  }

  // epilogue
  float bv[2];
  bv[0] = bias[n0 + wc*32      + mr];
  bv[1] = bias[n0 + wc*32 + 16 + mr];
#pragma unroll
  for (int mb = 0; mb < 2; ++mb) {
#pragma unroll
    for (int nb = 0; nb < 2; ++nb) {
      floatx4 d = acc[mb][nb];
      const int n = n0 + wc*32 + nb*16 + mr;
#pragma unroll
      for (int r = 0; r < 4; ++r) {
        const int m = m0 + wr*32 + mb*16 + q*4 + r;
        float v = (d[r] + bv[nb]) * scale;
        if (MODE == 0) {
          ((float*)outv)[(size_t)m * N + n] = v;
        } else {
          const int b = m >> 11, s = m & 2047, h = n >> 6, dd = n & 63;
          ((u16*)outv)[((((size_t)b * NHEAD + h) * SEQ + s) << 6) + dd] = f2bf(v);
        }
      }
    }
  }
}

// ---------------------------------------------------------------------------
// Causal attention, fp32 VALU. Grid (SEQ/256, B*H). One thread = one query
// row; q and the fp32 accumulator in registers (16 float4 each); K/V tiles
// (64 keys x 64 dims) staged to LDS as fp32. Inner-loop LDS reads are
// wave-uniform -> broadcast (conflict-free). Online softmax per thread;
// rescale only when the running max moves. Q pre-scaled by 1/8.
// ---------------------------------------------------------------------------
__global__ __launch_bounds__(256, 3)
void attn_fwd(const u16* __restrict__ Q, const u16* __restrict__ K,
              const u16* __restrict__ V, u16* __restrict__ O)
{
  __shared__ float Ks[64][68];   // pad 64->68 to spread staging-store banks
  __shared__ float Vs[64][68];

  const int bh = blockIdx.y;            // b*16 + h
  const int r0 = blockIdx.x * 256;
  const int t  = threadIdx.x;
  const int r  = r0 + t;                // this thread's query row

  // load my q row (64 bf16) into registers as 16 float4
  float4 q4[16];
  {
    const u16* Qp = Q + ((size_t)bh * SEQ + r) * DK;
#pragma unroll
    for (int c = 0; c < 8; ++c) {
      uint4 u = *(const uint4*)(Qp + c*8);
      q4[c*2+0] = make_float4(bflo(u.x), bfhi(u.x), bflo(u.y), bfhi(u.y));
      q4[c*2+1] = make_float4(bflo(u.z), bfhi(u.z), bflo(u.w), bfhi(u.w));
    }
  }

  float mx = -INFINITY, l = 0.0f;
  float4 acc4[16];
#pragma unroll
  for (int c = 0; c < 16; ++c) acc4[c] = make_float4(0.f, 0.f, 0.f, 0.f);

  // staging assignment: thread -> (key row jjs, 16-elem chunk cc)
  const int jjs = t >> 2, cc = t & 3;
  const u16* Kp = K + ((size_t)bh * SEQ + jjs) * DK + cc * 16;
  const u16* Vp = V + ((size_t)bh * SEQ + jjs) * DK + cc * 16;

  const int jend = r0 + 256;            // causal: keys < r0+256 suffice
  for (int j0 = 0; j0 < jend; j0 += 64) {
    __syncthreads();
    {
      const u16* kp = Kp + (size_t)j0 * DK;
      uint4 a = *(const uint4*)kp;
      uint4 b = *(const uint4*)(kp + 8);
      float* kd = &Ks[jjs][cc*16];
      kd[0]=bflo(a.x); kd[1]=bfhi(a.x); kd[2]=bflo(a.y); kd[3]=bfhi(a.y);
      kd[4]=bflo(a.z); kd[5]=bfhi(a.z); kd[6]=bflo(a.w); kd[7]=bfhi(a.w);
      kd[8]=bflo(b.x); kd[9]=bfhi(b.x); kd[10]=bflo(b.y); kd[11]=bfhi(b.y);
      kd[12]=bflo(b.z); kd[13]=bfhi(b.z); kd[14]=bflo(b.w); kd[15]=bfhi(b.w);
      const u16* vp = Vp + (size_t)j0 * DK;
      uint4 c0 = *(const uint4*)vp;
      uint4 c1 = *(const uint4*)(vp + 8);
      float* vd = &Vs[jjs][cc*16];
      vd[0]=bflo(c0.x); vd[1]=bfhi(c0.x); vd[2]=bflo(c0.y); vd[3]=bfhi(c0.y);
      vd[4]=bflo(c0.z); vd[5]=bfhi(c0.z); vd[6]=bflo(c0.w); vd[7]=bfhi(c0.w);
      vd[8]=bflo(c1.x); vd[9]=bfhi(c1.x); vd[10]=bflo(c1.y); vd[11]=bfhi(c1.y);
      vd[12]=bflo(c1.z); vd[13]=bfhi(c1.z); vd[14]=bflo(c1.w); vd[15]=bfhi(c1.w);
    }
    __syncthreads();

    for (int jj = 0; jj < 64; ++jj) {
      if (j0 + jj <= r) {               // causal mask (diagonal included)
        float4 p4 = make_float4(0.f, 0.f, 0.f, 0.f);
#pragma unroll
        for (int c = 0; c < 16; ++c) {
          const float4 k4 = *(const float4*)&Ks[jj][c*4];
          p4.x = fmaf(q4[c].x, k4.x, p4.x);
          p4.y = fmaf(q4[c].y, k4.y, p4.y);
          p4.z = fmaf(q4[c].z, k4.z, p4.z);
          p4.w = fmaf(q4[c].w, k4.w, p4.w);
        }
        const float s = (p4.x + p4.y) + (p4.z + p4.w);
        const float nm = fmaxf(mx, s);
        if (nm > mx) {                  // running max moved: rescale state
          const float corr = __expf(mx - nm);   // exp(-inf)=0 on first hit
          l *= corr;
#pragma unroll
          for (int c = 0; c < 16; ++c) {
            acc4[c].x *= corr; acc4[c].y *= corr;
            acc4[c].z *= corr; acc4[c].w *= corr;
          }
          mx = nm;
        }
        const float p = __expf(s - mx);
        l += p;
#pragma unroll
        for (int c = 0; c < 16; ++c) {
          const float4 v4 = *(const float4*)&Vs[jj][c*4];
          acc4[c].x = fmaf(p, v4.x, acc4[c].x);
          acc4[c].y = fmaf(p, v4.y, acc4[c].y);
          acc4[c].z = fmaf(p, v4.z, acc4[c].z);
          acc4[c].w = fmaf(p, v4.w, acc4[c].w);
        }
      }
    }
  }

  // epilogue: O in [B,S,D] layout (un-split heads), bf16, for final projection
  const float inv = 1.0f / l;           // l >= 1: diagonal always active
  const int b = bh >> 4, h = bh & 15;
  u16* Op = O + ((size_t)(b * SEQ + r)) * D_MODEL + h * DK;
#pragma unroll
  for (int c = 0; c < 16; ++c) {
    u32 p0 = ((u32)f2bf(acc4[c].y * inv) << 16) | f2bf(acc4[c].x * inv);
    u32 p1 = ((u32)f2bf(acc4[c].w * inv) << 16) | f2bf(acc4[c].z * inv);
    *(uint2*)(Op + c*4) = make_uint2(p0, p1);
  }
}

// ---------------------------------------------------------------------------
extern "C" void kernel_launch(void* const* d_in, const int* in_sizes, int n_in,
                              void* d_out, int out_size, void* d_ws, size_t ws_size,
                              hipStream_t stream)
{
  const float* x  = (const float*)d_in[0];
  const float* Wq = (const float*)d_in[1];
  const float* bq = (const float*)d_in[2];
  const float* Wk = (const float*)d_in[3];
  const float* bk = (const float*)d_in[4];
  const float* Wv = (const float*)d_in[5];
  const float* bv = (const float*)d_in[6];
  const float* Wo = (const float*)d_in[7];
  const float* bo = (const float*)d_in[8];
  float* outp = (float*)d_out;

  const size_t tsz = (size_t)MTOT * D_MODEL;   // 8.39M elements per tensor
  u16* Qw = (u16*)d_ws;
  u16* Kw = Qw + tsz;
  u16* Vw = Kw + tsz;
  u16* Ow = Vw + tsz;                           // 64 MB of ws total (bf16)

  dim3 gg(D_MODEL/64, MTOT/64);                 // 16 x 128 tiles
  // Q pre-scaled by 1/sqrt(dk)=1/8 (exact power of two -> lossless in bf16)
  gemm_bt<1,1><<<gg, 256, 0, stream>>>(x, Wq, bq, Qw, MTOT, D_MODEL, D_MODEL, 0.125f);
  gemm_bt<1,1><<<gg, 256, 0, stream>>>(x, Wk, bk, Kw, MTOT, D_MODEL, D_MODEL, 1.0f);
  gemm_bt<1,1><<<gg, 256, 0, stream>>>(x, Wv, bv, Vw, MTOT, D_MODEL, D_MODEL, 1.0f);

  attn_fwd<<<dim3(SEQ/256, BATCH*NHEAD), 256, 0, stream>>>(Qw, Kw, Vw, Ow);

  gemm_bt<0,0><<<gg, 256, 0, stream>>>(Ow, Wo, bo, outp, MTOT, D_MODEL, D_MODEL, 1.0f);
}

// Round 3
// 474.361 us; speedup vs baseline: 4.2229x; 4.2229x over previous
//
#include <hip/hip_runtime.h>
#include <stdint.h>

// CausalMultiHeadAttention — round 3: MFMA flash attention.
// fp32 in memory; 16-bit MFMA compute. Pipeline:
//   1) Q/K/V projections: bf16 MFMA GEMM; outputs fp16 ws. Q scaled by
//      0.125*log2e (softmax in log2 domain -> raw v_exp_f32). V written
//      TRANSPOSED per head [bh][d][s] so attention stages V^T coalesced.
//   2) flash attention: S^T = K*Q^T (16x16x32 f16 MFMA); S^T C-layout ==
//      B-operand layout of 16x16x16 f16 MFMA -> O^T = V^T * P^T with the
//      P conversion done entirely in-lane (no LDS round-trip). Online
//      softmax keyed by query=lane&15 (consistent across S^T and O^T).
//   3) output projection: bf16 O ws @ Wo^T -> fp32 d_out.
// ws: Qw | Kw | Vtw (fp16) | Ow (bf16), 16 MB each = 64 MB.

#define D_MODEL 1024
#define NHEAD   16
#define DK      64
#define BATCH   4
#define SEQ     2048
#define MTOT    (BATCH*SEQ)   // 8192

typedef unsigned short u16;
typedef unsigned int   u32;
typedef __bf16    bf16x8  __attribute__((ext_vector_type(8)));
typedef float     floatx4 __attribute__((ext_vector_type(4)));
typedef _Float16  half4_t __attribute__((ext_vector_type(4)));
typedef _Float16  half8_t __attribute__((ext_vector_type(8)));

// round-to-nearest-even f32 -> bf16
__device__ __forceinline__ u16 f2bf(float f){
  union { float f; u32 u; } c; c.f = f;
  u32 x = c.u;
  x += 0x7fffu + ((x >> 16) & 1u);
  return (u16)(x >> 16);
}
__device__ __forceinline__ u16 f2h(float f){
  union { _Float16 h[2]; u16 u[2]; } c; c.h[0] = (_Float16)f; return c.u[0];
}
// load 8 fp32, round to bf16, pack as uint4 (16 B) for LDS staging
__device__ __forceinline__ uint4 cvt8(const float* __restrict__ p){
  float4 a = *(const float4*)p;
  float4 b = *(const float4*)(p + 4);
  uint4 r;
  r.x = ((u32)f2bf(a.y) << 16) | f2bf(a.x);
  r.y = ((u32)f2bf(a.w) << 16) | f2bf(a.z);
  r.z = ((u32)f2bf(b.y) << 16) | f2bf(b.x);
  r.w = ((u32)f2bf(b.w) << 16) | f2bf(b.z);
  return r;
}

// ---------------------------------------------------------------------------
// GEMM: C[m,n] = (sum_k A[m,k] * W[n,k] + bias[n]) * scale
// MODE 0: out fp32 [m*N+n]                  (final projection -> d_out)
// MODE 1: out fp16 [bh][s][dk] head-major   (Q, K)
// MODE 2: out fp16 [bh][dk][s] transposed   (V)
// AF32: A is fp32 (convert to bf16 during staging) else bf16.
// 64x64 tile, BK=32, 4 waves in 2x2, 2x2 MFMAs each. (m89/m91-verified maps)
// ---------------------------------------------------------------------------
template<int MODE, int AF32>
__global__ __launch_bounds__(256, 4)
void gemm_bt(const void* __restrict__ Av, const float* __restrict__ W,
             const float* __restrict__ bias, void* __restrict__ outv,
             int M, int N, int K, float scale)
{
  __shared__ __align__(16) u16 As[64][40];
  __shared__ __align__(16) u16 Bs[64][40];

  const int t    = threadIdx.x;
  const int m0   = blockIdx.y * 64;
  const int n0   = blockIdx.x * 64;
  const int wid  = t >> 6;
  const int lane = t & 63;
  const int wr   = wid >> 1;
  const int wc   = wid & 1;
  const int q    = lane >> 4;
  const int mr   = lane & 15;

  const int srow = t >> 2;
  const int sc   = (t & 3) * 8;
  const float* Af = (const float*)Av;
  const u16*   Ab = (const u16*)Av;
  const size_t aoff = (size_t)(m0 + srow) * K + sc;
  const size_t woff = (size_t)(n0 + srow) * K + sc;

  floatx4 acc[2][2] = {};

  for (int k0 = 0; k0 < K; k0 += 32) {
    __syncthreads();
    if (AF32) *(uint4*)&As[srow][sc] = cvt8(Af + aoff + k0);
    else      *(uint4*)&As[srow][sc] = *(const uint4*)(Ab + aoff + k0);
    *(uint4*)&Bs[srow][sc] = cvt8(W + woff + k0);
    __syncthreads();

    bf16x8 af0 = *(const bf16x8*)&As[wr*32      + mr][q*8];
    bf16x8 af1 = *(const bf16x8*)&As[wr*32 + 16 + mr][q*8];
    bf16x8 bf0 = *(const bf16x8*)&Bs[wc*32      + mr][q*8];
    bf16x8 bf1 = *(const bf16x8*)&Bs[wc*32 + 16 + mr][q*8];

    acc[0][0] = __builtin_amdgcn_mfma_f32_16x16x32_bf16(af0, bf0, acc[0][0], 0, 0, 0);
    acc[0][1] = __builtin_amdgcn_mfma_f32_16x16x32_bf16(af0, bf1, acc[0][1], 0, 0, 0);
    acc[1][0] = __builtin_amdgcn_mfma_f32_16x16x32_bf16(af1, bf0, acc[1][0], 0, 0, 0);
    acc[1][1] = __builtin_amdgcn_mfma_f32_16x16x32_bf16(af1, bf1, acc[1][1], 0, 0, 0);
  }

  float bv[2];
  bv[0] = bias[n0 + wc*32      + mr];
  bv[1] = bias[n0 + wc*32 + 16 + mr];
#pragma unroll
  for (int mb = 0; mb < 2; ++mb) {
#pragma unroll
    for (int nb = 0; nb < 2; ++nb) {
      floatx4 d = acc[mb][nb];
      const int n = n0 + wc*32 + nb*16 + mr;
#pragma unroll
      for (int r = 0; r < 4; ++r) {
        const int m = m0 + wr*32 + mb*16 + q*4 + r;
        float v = (d[r] + bv[nb]) * scale;
        if (MODE == 0) {
          ((float*)outv)[(size_t)m * N + n] = v;
        } else {
          const int b = m >> 11, s = m & 2047, h = n >> 6, dd = n & 63;
          const size_t bh = (size_t)b * NHEAD + h;
          if (MODE == 1)
            ((u16*)outv)[((bh * SEQ + s) << 6) + dd] = f2h(v);
          else
            ((u16*)outv)[(bh * DK + dd) * SEQ + s] = f2h(v);
        }
      }
    }
  }
}

// ---------------------------------------------------------------------------
// MFMA flash attention. Grid (SEQ/128, B*H), 256 threads = 4 waves, 32
// queries per wave (2 subtiles of 16). K-loop: 64 keys/iter staged to LDS
// (K row-major per head; V pre-transposed [d][s] per head).
//  phase 1: S^T = K·Q^T via mfma_f32_16x16x32_f16:
//           A = K-frag (m=key=lane&15, k=d=quad*8+j) from LDS
//           B = Q-frag (n=query=lane&15, k=d) from registers
//           C: col=query=lane&15, row=key=quad*4+reg
//  softmax: stats per query=lane&15 (in-lane 16 + shfl_xor 16,32);
//           Q was pre-scaled by 0.125*log2e -> exp2f directly.
//  phase 2: O^T = V^T·P^T via mfma_f32_16x16x16f16:
//           A = V^T-frag (m=d=lane&15, k=key=quad*4+j) from LDS
//           B = P^T-frag (n=query=lane&15, k=key=quad*4+j) == S^T C-layout,
//               converted in-lane; O^T C: col=query=lane&15 -> alpha & 1/l
//               apply lane-locally.
// ---------------------------------------------------------------------------
__global__ __launch_bounds__(256, 3)
void attn_fwd(const _Float16* __restrict__ Q, const _Float16* __restrict__ K,
              const _Float16* __restrict__ Vt, u16* __restrict__ O)
{
  __shared__ __align__(16) _Float16 Ks[64][72];  // [key][d], pad 64->72
  __shared__ __align__(16) _Float16 Vs[64][72];  // [d][key], pad

  const int bh   = blockIdx.y;
  const int r0   = blockIdx.x * 128;
  const int t    = threadIdx.x;
  const int w    = t >> 6, lane = t & 63;
  const int quad = lane >> 4, l15 = lane & 15;
  const int qb   = r0 + w * 32;              // wave's first query

  // Q fragments (B-operand of 16x16x32): [qsub][kstep(32)] = 8 f16
  half8_t qf[2][2];
  {
    const _Float16* Qp = Q + ((size_t)bh * SEQ + qb + l15) * DK + quad * 8;
#pragma unroll
    for (int qs = 0; qs < 2; ++qs)
#pragma unroll
      for (int ks = 0; ks < 2; ++ks)
        qf[qs][ks] = *(const half8_t*)(Qp + qs * 16 * DK + ks * 32);
  }

  float mrow[2] = { -1e30f, -1e30f };
  float lrow[2] = { 0.f, 0.f };
  floatx4 o[2][4] = {};                      // [qsub][dtile], O^T C-layout

  const int jend = r0 + 128;
  for (int j0 = 0; j0 < jend; j0 += 64) {
    __syncthreads();
#pragma unroll
    for (int it = 0; it < 2; ++it) {         // stage 8KB K + 8KB V^T
      const int idx = t + it * 256;
      const int row = idx >> 3, ch = (idx & 7) * 8;
      *(uint4*)&Ks[row][ch] = *(const uint4*)(K  + ((size_t)bh * SEQ + j0 + row) * DK + ch);
      *(uint4*)&Vs[row][ch] = *(const uint4*)(Vt + ((size_t)bh * DK  + row) * SEQ + j0 + ch);
    }
    __syncthreads();
    if (j0 > qb + 31) continue;              // tile fully masked for wave

    // ---- phase 1: S^T tiles
    floatx4 st[2][4] = {};
#pragma unroll
    for (int kt = 0; kt < 4; ++kt)
#pragma unroll
      for (int ks = 0; ks < 2; ++ks) {
        half8_t af = *(const half8_t*)&Ks[kt * 16 + l15][ks * 32 + quad * 8];
        st[0][kt] = __builtin_amdgcn_mfma_f32_16x16x32_f16(af, qf[0][ks], st[0][kt], 0, 0, 0);
        st[1][kt] = __builtin_amdgcn_mfma_f32_16x16x32_f16(af, qf[1][ks], st[1][kt], 0, 0, 0);
      }

    // ---- mask + online softmax (log2 domain), build P^T B-fragments
    half4_t pf[2][4];
#pragma unroll
    for (int qs = 0; qs < 2; ++qs) {
      const int query = qb + qs * 16 + l15;
      if (j0 + 63 > qb + qs * 16) {          // wave-uniform: masking needed
#pragma unroll
        for (int kt = 0; kt < 4; ++kt)
#pragma unroll
          for (int r = 0; r < 4; ++r)
            if (j0 + kt * 16 + quad * 4 + r > query) st[qs][kt][r] = -1e30f;
      }
      float m0 = st[qs][0][0];
#pragma unroll
      for (int kt = 0; kt < 4; ++kt)
#pragma unroll
        for (int r = 0; r < 4; ++r) m0 = fmaxf(m0, st[qs][kt][r]);
      m0 = fmaxf(m0, __shfl_xor(m0, 16));
      m0 = fmaxf(m0, __shfl_xor(m0, 32));
      const float mn    = fmaxf(mrow[qs], m0);
      const float alpha = exp2f(mrow[qs] - mn);
      mrow[qs] = mn;
      float ls = 0.f;
#pragma unroll
      for (int kt = 0; kt < 4; ++kt)
#pragma unroll
        for (int r = 0; r < 4; ++r) {
          const float p = exp2f(st[qs][kt][r] - mn);
          ls += p;
          pf[qs][kt][r] = (_Float16)p;
        }
      ls += __shfl_xor(ls, 16);
      ls += __shfl_xor(ls, 32);
      lrow[qs] = lrow[qs] * alpha + ls;
#pragma unroll
      for (int dt = 0; dt < 4; ++dt) {
        o[qs][dt][0] *= alpha; o[qs][dt][1] *= alpha;
        o[qs][dt][2] *= alpha; o[qs][dt][3] *= alpha;
      }
    }

    // ---- phase 2: O^T += V^T · P^T
#pragma unroll
    for (int dt = 0; dt < 4; ++dt)
#pragma unroll
      for (int kt = 0; kt < 4; ++kt) {
        half4_t vf = *(const half4_t*)&Vs[dt * 16 + l15][kt * 16 + quad * 4];
        o[0][dt] = __builtin_amdgcn_mfma_f32_16x16x16f16(vf, pf[0][kt], o[0][dt], 0, 0, 0);
        o[1][dt] = __builtin_amdgcn_mfma_f32_16x16x16f16(vf, pf[1][kt], o[1][dt], 0, 0, 0);
      }
  }

  // ---- epilogue: O[query][d] bf16 in [B,S,D] (un-split heads)
  const int b = bh >> 4, h = bh & 15;
#pragma unroll
  for (int qs = 0; qs < 2; ++qs) {
    const float inv = 1.0f / lrow[qs];
    const int query = qb + qs * 16 + l15;
    u16* Op = O + ((size_t)(b * SEQ + query)) * D_MODEL + h * DK + quad * 4;
#pragma unroll
    for (int dt = 0; dt < 4; ++dt) {
      u32 lo = ((u32)f2bf(o[qs][dt][1] * inv) << 16) | f2bf(o[qs][dt][0] * inv);
      u32 hi = ((u32)f2bf(o[qs][dt][3] * inv) << 16) | f2bf(o[qs][dt][2] * inv);
      *(uint2*)(Op + dt * 16) = make_uint2(lo, hi);
    }
  }
}

// ---------------------------------------------------------------------------
extern "C" void kernel_launch(void* const* d_in, const int* in_sizes, int n_in,
                              void* d_out, int out_size, void* d_ws, size_t ws_size,
                              hipStream_t stream)
{
  const float* x  = (const float*)d_in[0];
  const float* Wq = (const float*)d_in[1];
  const float* bq = (const float*)d_in[2];
  const float* Wk = (const float*)d_in[3];
  const float* bk = (const float*)d_in[4];
  const float* Wv = (const float*)d_in[5];
  const float* bv = (const float*)d_in[6];
  const float* Wo = (const float*)d_in[7];
  const float* bo = (const float*)d_in[8];
  float* outp = (float*)d_out;

  const size_t tsz = (size_t)MTOT * D_MODEL;
  u16* Qw  = (u16*)d_ws;
  u16* Kw  = Qw + tsz;
  u16* Vtw = Kw + tsz;
  u16* Ow  = Vtw + tsz;                       // 64 MB total

  dim3 gg(D_MODEL/64, MTOT/64);
  // Q scale = 1/sqrt(dk) * log2(e): softmax runs in log2 domain
  gemm_bt<1,1><<<gg, 256, 0, stream>>>(x, Wq, bq, Qw,  MTOT, D_MODEL, D_MODEL, 0.18033688f);
  gemm_bt<1,1><<<gg, 256, 0, stream>>>(x, Wk, bk, Kw,  MTOT, D_MODEL, D_MODEL, 1.0f);
  gemm_bt<2,1><<<gg, 256, 0, stream>>>(x, Wv, bv, Vtw, MTOT, D_MODEL, D_MODEL, 1.0f);

  attn_fwd<<<dim3(SEQ/128, BATCH*NHEAD), 256, 0, stream>>>(
      (const _Float16*)Qw, (const _Float16*)Kw, (const _Float16*)Vtw, Ow);

  gemm_bt<0,0><<<gg, 256, 0, stream>>>(Ow, Wo, bo, outp, MTOT, D_MODEL, D_MODEL, 1.0f);
}

// Round 5
// 454.680 us; speedup vs baseline: 4.4056x; 1.0433x over previous
//
#include <hip/hip_runtime.h>
#include <stdint.h>

// CausalMultiHeadAttention — round 5 (= round 4 + cvt_pkrtz type fix).
// fp32 in memory; 16-bit MFMA compute.
//  - GEMM: 128x128 tile (16 MFMA/K-step/wave), v_perm trunc-pack staging,
//    per-mode operand order so all epilogues store vectorized (float4/uint2).
//  - Attention: 64 queries/block (16/wave) -> 2048 blocks = 8/CU (LDS-exact),
//    reversed dispatch (heavy tiles first), wave-uniform subtile skip on the
//    diagonal, deferred l-reduction (no shfl in the per-tile chain).
// ws: Q | K | Vt (fp16) | O (bf16), 16.8 MB each = 67.1 MB (proven size).

#define D_MODEL 1024
#define NHEAD   16
#define DK      64
#define BATCH   4
#define SEQ     2048
#define MTOT    (BATCH*SEQ)   // 8192

typedef unsigned short u16;
typedef unsigned int   u32;
typedef __bf16    bf16x8  __attribute__((ext_vector_type(8)));
typedef float     floatx4 __attribute__((ext_vector_type(4)));
typedef __fp16    fp16x2  __attribute__((ext_vector_type(2)));   // cvt_pkrtz native
typedef _Float16  half4_t __attribute__((ext_vector_type(4)));
typedef _Float16  half8_t __attribute__((ext_vector_type(8)));

// round-to-nearest-even f32 -> bf16 (epilogue only)
__device__ __forceinline__ u16 f2bf(float f){
  union { float f; u32 u; } c; c.f = f;
  u32 x = c.u;
  x += 0x7fffu + ((x >> 16) & 1u);
  return (u16)(x >> 16);
}
// f32 pair -> packed fp16 bits (RTZ, hardware packed cvt)
__device__ __forceinline__ u32 pkh(float a, float b){
  union { fp16x2 h; u32 u; } c; c.h = __builtin_amdgcn_cvt_pkrtz(a, b); return c.u;
}
// 8 fp32 -> 8 bf16 by truncation: one v_perm per pair (staging fast path)
__device__ __forceinline__ uint4 pk8(const float* __restrict__ p){
  uint4 a = *(const uint4*)p;
  uint4 b = *(const uint4*)(p + 4);
  uint4 r;
  r.x = __builtin_amdgcn_perm(a.y, a.x, 0x07060302);
  r.y = __builtin_amdgcn_perm(a.w, a.z, 0x07060302);
  r.z = __builtin_amdgcn_perm(b.y, b.x, 0x07060302);
  r.w = __builtin_amdgcn_perm(b.w, b.z, 0x07060302);
  return r;
}

// ---------------------------------------------------------------------------
// GEMM: C[m,n] = (sum_k A[m,k]*W[n,k] + bias[n]) * scale.  A: MxK row-major
// (fp32, or bf16 if ABF16).  W: NxK fp32 row-major (nn.Linear weight).
// 128x128 tile, BK=32, 256 thr = 4 waves in 2x2, each wave 64x64 = 4x4 MFMA.
// Operand order is mode-specialized so the C-fragment's 4 regs run along the
// output's fast axis:
//   MODE 0 (fp32 [m][N], d_out) / MODE 1 (fp16 [bh][s][dk]): mfma(W,A) ->
//     lane=m, regs=n-consecutive -> float4 / uint2 stores.
//   MODE 2 (fp16 [bh][dk][s], V^T): mfma(A,W) -> lane=n(dd), regs=m(s)
//     -> uint2 stores contiguous in s.
// ---------------------------------------------------------------------------
template<int MODE, int ABF16>
__global__ __launch_bounds__(256, 2)
void gemm_bt(const void* __restrict__ Av, const float* __restrict__ W,
             const float* __restrict__ bias, void* __restrict__ outv,
             float scale)
{
  __shared__ __align__(16) u16 As[128*32];
  __shared__ __align__(16) u16 Bs[128*32];

  const int t    = threadIdx.x;
  const int n0   = blockIdx.x * 128;
  const int m0   = blockIdx.y * 128;
  const int wid  = t >> 6, lane = t & 63;
  const int wr   = wid >> 1, wc = wid & 1;
  const int quad = lane >> 4, l15 = lane & 15;

  // staging chunks: c -> row = c>>2, koff = (c&3)*8 ; LDS layout [row][32]
  const int c0 = t, c1 = t + 256;
  const int r0c = c0 >> 2, k0c = (c0 & 3) * 8;
  const int r1c = c1 >> 2, k1c = (c1 & 3) * 8;

  const float* Af = (const float*)Av;
  const u16*   Ab = (const u16*)Av;

  floatx4 acc[4][4] = {};

  for (int k0 = 0; k0 < D_MODEL; k0 += 32) {
    __syncthreads();
    if (ABF16) {
      *(uint4*)&As[c0*8] = *(const uint4*)(Ab + (size_t)(m0 + r0c)*D_MODEL + k0 + k0c);
      *(uint4*)&As[c1*8] = *(const uint4*)(Ab + (size_t)(m0 + r1c)*D_MODEL + k0 + k1c);
    } else {
      *(uint4*)&As[c0*8] = pk8(Af + (size_t)(m0 + r0c)*D_MODEL + k0 + k0c);
      *(uint4*)&As[c1*8] = pk8(Af + (size_t)(m0 + r1c)*D_MODEL + k0 + k1c);
    }
    *(uint4*)&Bs[c0*8] = pk8(W + (size_t)(n0 + r0c)*D_MODEL + k0 + k0c);
    *(uint4*)&Bs[c1*8] = pk8(W + (size_t)(n0 + r1c)*D_MODEL + k0 + k1c);
    __syncthreads();

    bf16x8 af[4], bf[4];
#pragma unroll
    for (int i = 0; i < 4; ++i) {
      af[i] = *(const bf16x8*)&As[(wr*64 + i*16 + l15)*32 + quad*8];
      bf[i] = *(const bf16x8*)&Bs[(wc*64 + i*16 + l15)*32 + quad*8];
    }
#pragma unroll
    for (int mi = 0; mi < 4; ++mi)
#pragma unroll
      for (int nj = 0; nj < 4; ++nj) {
        if (MODE == 2)
          acc[mi][nj] = __builtin_amdgcn_mfma_f32_16x16x32_bf16(af[mi], bf[nj], acc[mi][nj], 0, 0, 0);
        else
          acc[mi][nj] = __builtin_amdgcn_mfma_f32_16x16x32_bf16(bf[nj], af[mi], acc[mi][nj], 0, 0, 0);
      }
  }

  if (MODE != 2) {
    // lane = m, regs = n-consecutive
#pragma unroll
    for (int nj = 0; nj < 4; ++nj) {
      const int nb = n0 + wc*64 + nj*16 + quad*4;
      const float4 b4 = *(const float4*)(bias + nb);
#pragma unroll
      for (int mi = 0; mi < 4; ++mi) {
        const int m = m0 + wr*64 + mi*16 + l15;
        floatx4 d = acc[mi][nj];
        const float v0 = (d[0]+b4.x)*scale, v1 = (d[1]+b4.y)*scale;
        const float v2 = (d[2]+b4.z)*scale, v3 = (d[3]+b4.w)*scale;
        if (MODE == 0) {
          float4 s4 = make_float4(v0, v1, v2, v3);
          *(float4*)((float*)outv + (size_t)m*D_MODEL + nb) = s4;
        } else {
          const int b = m >> 11, s = m & 2047, h = nb >> 6, dd = nb & 63;
          u16* dst = (u16*)outv + ((((size_t)b*NHEAD + h)*SEQ + s) << 6) + dd;
          *(uint2*)dst = make_uint2(pkh(v0, v1), pkh(v2, v3));
        }
      }
    }
  } else {
    // lane = n (dd), regs = m (s)-consecutive
#pragma unroll
    for (int nj = 0; nj < 4; ++nj) {
      const int n  = n0 + wc*64 + nj*16 + l15;
      const float bvv = bias[n];
      const int h = n >> 6, dd = n & 63;
#pragma unroll
      for (int mi = 0; mi < 4; ++mi) {
        const int mb = m0 + wr*64 + mi*16 + quad*4;
        const int b = mb >> 11, s = mb & 2047;
        floatx4 d = acc[mi][nj];
        u16* dst = (u16*)outv + (((size_t)b*NHEAD + h)*DK + dd)*SEQ + s;
        *(uint2*)dst = make_uint2(pkh(d[0]+bvv, d[1]+bvv), pkh(d[2]+bvv, d[3]+bvv));
      }
    }
  }
}

// ---------------------------------------------------------------------------
// MFMA flash attention. Grid (SEQ/64 reversed, B*H), 256 thr = 4 waves,
// 16 queries per wave. 64-key tiles staged to LDS (K [key][d], V^T [d][key]).
//  phase 1: S^T = K·Q^T (16x16x32 f16); C: col=query=lane&15, row=key.
//  softmax: per-query stats; l kept per-lane-partial, reduced in epilogue.
//  phase 2: O^T = V^T·P^T (16x16x16 f16); P^T B-frag == S^T C-layout.
// Wave-uniform ktmax skips fully-masked 16-key subtiles on the diagonal.
// ---------------------------------------------------------------------------
__global__ __launch_bounds__(256, 6)
void attn_fwd(const _Float16* __restrict__ Q, const _Float16* __restrict__ K,
              const _Float16* __restrict__ Vt, u16* __restrict__ O)
{
  __shared__ __align__(16) _Float16 Ks[64][72];
  __shared__ __align__(16) _Float16 Vs[64][72];

  const int bh   = blockIdx.y;
  const int r0   = ((int)gridDim.x - 1 - (int)blockIdx.x) * 64;  // heavy first
  const int t    = threadIdx.x;
  const int w    = t >> 6, lane = t & 63;
  const int quad = lane >> 4, l15 = lane & 15;
  const int qb   = r0 + w * 16;
  const int query = qb + l15;

  half8_t qf[2];
  {
    const _Float16* Qp = Q + ((size_t)bh * SEQ + query) * DK + quad * 8;
    qf[0] = *(const half8_t*)(Qp);
    qf[1] = *(const half8_t*)(Qp + 32);
  }

  float mrow = -1e30f, lpart = 0.f;
  floatx4 o[4] = {};

  const int sr = t >> 3, sc8 = (t & 7) * 8;
  const _Float16* Kb = K  + (size_t)bh * SEQ * DK;
  const _Float16* Vb = Vt + (size_t)bh * DK * SEQ;

  const int jend = r0 + 64;
  for (int j0 = 0; j0 < jend; j0 += 64) {
    __syncthreads();
    *(uint4*)&Ks[sr     ][sc8] = *(const uint4*)(Kb + (size_t)(j0 + sr     )*DK + sc8);
    *(uint4*)&Ks[sr + 32][sc8] = *(const uint4*)(Kb + (size_t)(j0 + sr + 32)*DK + sc8);
    *(uint4*)&Vs[sr     ][sc8] = *(const uint4*)(Vb + (size_t)(sr     )*SEQ + j0 + sc8);
    *(uint4*)&Vs[sr + 32][sc8] = *(const uint4*)(Vb + (size_t)(sr + 32)*SEQ + j0 + sc8);
    __syncthreads();
    if (j0 > qb + 15) continue;                      // fully masked for wave
    const int ktmax = ((qb + 15 - j0) >> 4) + 1;     // 1..4, wave-uniform

    // ---- phase 1
    floatx4 st[4];
#pragma unroll
    for (int kt = 0; kt < 4; ++kt) {
      if (kt < ktmax) {
        half8_t a0 = *(const half8_t*)&Ks[kt*16 + l15][quad*8];
        half8_t a1 = *(const half8_t*)&Ks[kt*16 + l15][32 + quad*8];
        floatx4 s = {};
        s = __builtin_amdgcn_mfma_f32_16x16x32_f16(a0, qf[0], s, 0, 0, 0);
        s = __builtin_amdgcn_mfma_f32_16x16x32_f16(a1, qf[1], s, 0, 0, 0);
        st[kt] = s;
      }
    }
    // ---- causal mask (only subtiles straddling the diagonal)
#pragma unroll
    for (int kt = 0; kt < 4; ++kt) {
      if (kt < ktmax && j0 + kt*16 + 15 > qb) {
#pragma unroll
        for (int r = 0; r < 4; ++r)
          if (j0 + kt*16 + quad*4 + r > query) st[kt][r] = -1e30f;
      }
    }
    // ---- online softmax (log2 domain; Q pre-scaled by 0.125*log2e)
    float m0 = -1e30f;
#pragma unroll
    for (int kt = 0; kt < 4; ++kt)
      if (kt < ktmax)
        m0 = fmaxf(m0, fmaxf(fmaxf(st[kt][0], st[kt][1]), fmaxf(st[kt][2], st[kt][3])));
    m0 = fmaxf(m0, __shfl_xor(m0, 16));
    m0 = fmaxf(m0, __shfl_xor(m0, 32));
    const float mn    = fmaxf(mrow, m0);
    const float alpha = exp2f(mrow - mn);            // 0 on first live tile
    mrow = mn;
    lpart *= alpha;
    half4_t pf[4];
#pragma unroll
    for (int kt = 0; kt < 4; ++kt) {
      if (kt < ktmax) {
        const float p0 = exp2f(st[kt][0] - mn), p1 = exp2f(st[kt][1] - mn);
        const float p2 = exp2f(st[kt][2] - mn), p3 = exp2f(st[kt][3] - mn);
        lpart += (p0 + p1) + (p2 + p3);
        union { half4_t h; uint2 u; } pc;
        pc.u = make_uint2(pkh(p0, p1), pkh(p2, p3));
        pf[kt] = pc.h;
      }
    }
#pragma unroll
    for (int dt = 0; dt < 4; ++dt) {
      o[dt][0] *= alpha; o[dt][1] *= alpha; o[dt][2] *= alpha; o[dt][3] *= alpha;
    }
    // ---- phase 2
#pragma unroll
    for (int dt = 0; dt < 4; ++dt)
#pragma unroll
      for (int kt = 0; kt < 4; ++kt) {
        if (kt < ktmax) {
          half4_t vf = *(const half4_t*)&Vs[dt*16 + l15][kt*16 + quad*4];
          o[dt] = __builtin_amdgcn_mfma_f32_16x16x16f16(vf, pf[kt], o[dt], 0, 0, 0);
        }
      }
  }

  // ---- epilogue: deferred l reduction, O bf16 [B,S,D]
  float l = lpart;
  l += __shfl_xor(l, 16);
  l += __shfl_xor(l, 32);
  const float inv = 1.0f / l;
  const int b = bh >> 4, h = bh & 15;
  u16* Op = O + ((size_t)(b * SEQ + query)) * D_MODEL + h * DK + quad * 4;
#pragma unroll
  for (int dt = 0; dt < 4; ++dt) {
    u32 lo = ((u32)f2bf(o[dt][1] * inv) << 16) | f2bf(o[dt][0] * inv);
    u32 hi = ((u32)f2bf(o[dt][3] * inv) << 16) | f2bf(o[dt][2] * inv);
    *(uint2*)(Op + dt * 16) = make_uint2(lo, hi);
  }
}

// ---------------------------------------------------------------------------
extern "C" void kernel_launch(void* const* d_in, const int* in_sizes, int n_in,
                              void* d_out, int out_size, void* d_ws, size_t ws_size,
                              hipStream_t stream)
{
  const float* x  = (const float*)d_in[0];
  const float* Wq = (const float*)d_in[1];
  const float* bq = (const float*)d_in[2];
  const float* Wk = (const float*)d_in[3];
  const float* bk = (const float*)d_in[4];
  const float* Wv = (const float*)d_in[5];
  const float* bv = (const float*)d_in[6];
  const float* Wo = (const float*)d_in[7];
  const float* bo = (const float*)d_in[8];

  const size_t tsz = (size_t)MTOT * D_MODEL;
  u16* Qw  = (u16*)d_ws;
  u16* Kw  = Qw + tsz;
  u16* Vtw = Kw + tsz;
  u16* Ow  = Vtw + tsz;                        // 67.1 MB total

  dim3 gg(D_MODEL/128, MTOT/128);              // 8 x 64
  // Q scale = 1/sqrt(dk) * log2(e): softmax runs in log2 domain
  gemm_bt<1,0><<<gg, 256, 0, stream>>>(x, Wq, bq, Qw,  0.18033688f);
  gemm_bt<1,0><<<gg, 256, 0, stream>>>(x, Wk, bk, Kw,  1.0f);
  gemm_bt<2,0><<<gg, 256, 0, stream>>>(x, Wv, bv, Vtw, 1.0f);

  attn_fwd<<<dim3(SEQ/64, BATCH*NHEAD), 256, 0, stream>>>(
      (const _Float16*)Qw, (const _Float16*)Kw, (const _Float16*)Vtw, Ow);

  gemm_bt<0,1><<<gg, 256, 0, stream>>>(Ow, Wo, bo, d_out, 1.0f);
}